// Round 1
// baseline (771.732 us; speedup 1.0000x reference)
//
#include <hip/hip_runtime.h>
#include <math.h>

#define H     1024
#define FFN   4096
#define NE    8
#define TOK   2048
#define PAIRS (TOK*2)
#define BM    128
#define BK    32
#define ROWCAP (PAIRS + NE*BM)   /* 5120 worst-case padded rows */
#define MAXTILES (ROWCAP/BM)     /* 40 */

typedef unsigned short u16;
typedef __attribute__((ext_vector_type(8))) __bf16 bf16x8;
typedef __attribute__((ext_vector_type(4))) float  f32x4;

struct alignas(8) us4 { u16 x, y, z, w; };

__device__ __forceinline__ u16 f2bf(float f) {
    unsigned u = __builtin_bit_cast(unsigned, f);
    return (u16)((u + 0x7fffu + ((u >> 16) & 1u)) >> 16);
}

#define GLD16(gp, lp) __builtin_amdgcn_global_load_lds( \
    (const __attribute__((address_space(1))) void*)(gp), \
    (__attribute__((address_space(3))) void*)(lp), 16, 0, 0)

// ---------------- kernel 1: zero counts + xg ----------------
__global__ void k_zero(int* counts, uint4* xg4) {
    size_t i = (size_t)blockIdx.x * 256 + threadIdx.x;   // grid 2560*256 == ROWCAP*H/8
    if (i < (size_t)ROWCAP * H / 8) xg4[i] = uint4{0u, 0u, 0u, 0u};
    if (blockIdx.x == 0 && threadIdx.x < NE) counts[threadIdx.x] = 0;
}

// ---------------- kernel 2: router ----------------
__global__ void k_router(const float* __restrict__ x, const float* __restrict__ gw,
                         float* __restrict__ logits, int* counts,
                         int* __restrict__ sel, int* __restrict__ posn, float* __restrict__ wgt) {
    int lane = threadIdx.x & 63;
    int t = blockIdx.x * 4 + (threadIdx.x >> 6);
    float p[NE];
#pragma unroll
    for (int e = 0; e < NE; e++) p[e] = 0.f;
    for (int j = 0; j < H / 64; j++) {
        int h = lane + j * 64;
        float xv = x[(size_t)t * H + h];
#pragma unroll
        for (int e = 0; e < NE; e++) p[e] = fmaf(xv, gw[e * H + h], p[e]);
    }
#pragma unroll
    for (int off = 32; off; off >>= 1)
#pragma unroll
        for (int e = 0; e < NE; e++) p[e] += __shfl_xor(p[e], off, 64);
    if (lane == 0) {
        float mx = p[0];
#pragma unroll
        for (int e = 1; e < NE; e++) mx = fmaxf(mx, p[e]);
        float pe[NE];
#pragma unroll
        for (int e = 0; e < NE; e++) pe[e] = __expf(p[e] - mx);
        int i0 = 0;
#pragma unroll
        for (int e = 1; e < NE; e++) if (pe[e] > pe[i0]) i0 = e;
        int i1 = (i0 == 0) ? 1 : 0;
#pragma unroll
        for (int e = 0; e < NE; e++) if (e != i1 && e != i0 && pe[e] > pe[i1]) i1 = e;
        float w0 = pe[i0] / (pe[i0] + pe[i1]);
#pragma unroll
        for (int e = 0; e < NE; e++) logits[(size_t)t * NE + e] = p[e];
        int p0 = atomicAdd(&counts[i0], 1);
        int p1 = atomicAdd(&counts[i1], 1);
        sel[2 * t] = i0;  posn[2 * t] = p0;  wgt[2 * t] = w0;
        sel[2 * t + 1] = i1;  posn[2 * t + 1] = p1;  wgt[2 * t + 1] = 1.f - w0;
    }
}

// ---------------- kernel 3: prefix / tile map ----------------
__global__ void k_prefix(const int* __restrict__ counts, int* __restrict__ base,
                         int* __restrict__ tile_e) {
    if (threadIdx.x == 0) {
        int b = 0, tb = 0;
        for (int e = 0; e < NE; e++) {
            base[e] = b;
            int nt = (counts[e] + BM - 1) / BM;
            for (int i = 0; i < nt; i++) tile_e[tb++] = e;
            b += nt * BM;
        }
        base[NE] = b;
        while (tb < MAXTILES) tile_e[tb++] = -1;
    }
}

// ---------------- kernel 4: gather x -> bf16 compacted rows ----------------
__global__ void k_gather(const float4* __restrict__ x4, const int* __restrict__ sel,
                         const int* __restrict__ posn, const int* __restrict__ base,
                         u16* __restrict__ xg) {
    int p = blockIdx.x;
    int lane = threadIdx.x;       // 64 threads
    int t = p >> 1;
    int row = base[sel[p]] + posn[p];
#pragma unroll
    for (int i = 0; i < 4; i++) {
        int idx = i * 64 + lane;  // float4 index within row (256 per row)
        float4 v = x4[(size_t)t * (H / 4) + idx];
        us4 o = { f2bf(v.x), f2bf(v.y), f2bf(v.z), f2bf(v.w) };
        *(us4*)&xg[(size_t)row * H + idx * 4] = o;
    }
}

// ---------------- kernel 5: GEMM1  act = silu(x w1^T) * (x w3^T) ----------------
__global__ __launch_bounds__(256) void k_gemm1(const u16* __restrict__ xg,
                                               const float* __restrict__ w13,
                                               u16* __restrict__ act,
                                               const int* __restrict__ tile_e) {
    int e = tile_e[blockIdx.x];
    if (e < 0) return;
    __shared__ u16 As[BM * BK];          // 128x32 bf16, row-major K-contig
    __shared__ u16 Bs[2][64 * (BK + 8)]; // +8 pad breaks bank conflicts

    int tid = threadIdx.x;
    int lane = tid & 63, wave = tid >> 6;
    int quad = lane >> 4, m16 = lane & 15;
    int wm = wave >> 1, wn = wave & 1;
    int row0 = blockIdx.x * BM;
    int n0 = blockIdx.y * 64;
    const float* wb1 = w13 + ((size_t)e * 2 * FFN + n0) * H;
    const float* wb3 = w13 + ((size_t)e * 2 * FFN + FFN + n0) * H;

    f32x4 accg[4][2], accu[4][2];
#pragma unroll
    for (int mi = 0; mi < 4; mi++)
#pragma unroll
        for (int ni = 0; ni < 2; ni++) { accg[mi][ni] = {0.f,0.f,0.f,0.f}; accu[mi][ni] = {0.f,0.f,0.f,0.f}; }

    for (int kk = 0; kk < H; kk += BK) {
        // A tile: 128x32 bf16 = 512 x 16B chunks, 2 per thread, direct-to-LDS
#pragma unroll
        for (int i = 0; i < 2; i++) {
            int chunk = i * 256 + tid;
            int r = chunk >> 2, c = (chunk & 3) * 8;
            GLD16(xg + (size_t)(row0 + r) * H + kk + c, As + chunk * 8);
        }
        // B tiles (w1, w3): 64 rows x 8 float4 each; cvt fp32->bf16 into padded LDS
#pragma unroll
        for (int i = 0; i < 2; i++) {
            int idx = i * 256 + tid;
            int r = idx >> 3, c4 = idx & 7;
            float4 v1 = *(const float4*)(wb1 + (size_t)r * H + kk + c4 * 4);
            float4 v3 = *(const float4*)(wb3 + (size_t)r * H + kk + c4 * 4);
            us4 o1 = { f2bf(v1.x), f2bf(v1.y), f2bf(v1.z), f2bf(v1.w) };
            us4 o3 = { f2bf(v3.x), f2bf(v3.y), f2bf(v3.z), f2bf(v3.w) };
            *(us4*)&Bs[0][r * (BK + 8) + c4 * 4] = o1;
            *(us4*)&Bs[1][r * (BK + 8) + c4 * 4] = o3;
        }
        __syncthreads();
        bf16x8 a[4], bg[2], bu[2];
#pragma unroll
        for (int mi = 0; mi < 4; mi++)
            a[mi] = *(const bf16x8*)&As[(wm * 64 + mi * 16 + m16) * BK + quad * 8];
#pragma unroll
        for (int ni = 0; ni < 2; ni++) {
            bg[ni] = *(const bf16x8*)&Bs[0][(wn * 32 + ni * 16 + m16) * (BK + 8) + quad * 8];
            bu[ni] = *(const bf16x8*)&Bs[1][(wn * 32 + ni * 16 + m16) * (BK + 8) + quad * 8];
        }
#pragma unroll
        for (int mi = 0; mi < 4; mi++)
#pragma unroll
            for (int ni = 0; ni < 2; ni++) {
                accg[mi][ni] = __builtin_amdgcn_mfma_f32_16x16x32_bf16(a[mi], bg[ni], accg[mi][ni], 0, 0, 0);
                accu[mi][ni] = __builtin_amdgcn_mfma_f32_16x16x32_bf16(a[mi], bu[ni], accu[mi][ni], 0, 0, 0);
            }
        __syncthreads();
    }
    // epilogue: silu(g)*u -> bf16 act
#pragma unroll
    for (int mi = 0; mi < 4; mi++)
#pragma unroll
        for (int ni = 0; ni < 2; ni++)
#pragma unroll
            for (int r = 0; r < 4; r++) {
                float g = accg[mi][ni][r], u = accu[mi][ni][r];
                float hv = g * (1.f / (1.f + __expf(-g))) * u;
                int grow = row0 + wm * 64 + mi * 16 + quad * 4 + r;
                int gcol = n0 + wn * 32 + ni * 16 + m16;
                act[(size_t)grow * FFN + gcol] = f2bf(hv);
            }
}

// ---------------- kernel 6: GEMM2  yc = act w2^T ----------------
__global__ __launch_bounds__(256) void k_gemm2(const u16* __restrict__ act,
                                               const float* __restrict__ w2,
                                               float* __restrict__ yc,
                                               const int* __restrict__ tile_e) {
    int e = tile_e[blockIdx.x];
    if (e < 0) return;
    __shared__ u16 As[BM * BK];
    __shared__ u16 Bs[BM * (BK + 8)];

    int tid = threadIdx.x;
    int lane = tid & 63, wave = tid >> 6;
    int quad = lane >> 4, m16 = lane & 15;
    int wm = wave >> 1, wn = wave & 1;
    int row0 = blockIdx.x * BM;
    int n0 = blockIdx.y * 128;
    const float* wb = w2 + ((size_t)e * H + n0) * FFN;

    f32x4 acc[4][4];
#pragma unroll
    for (int mi = 0; mi < 4; mi++)
#pragma unroll
        for (int ni = 0; ni < 4; ni++) acc[mi][ni] = {0.f,0.f,0.f,0.f};

    for (int kk = 0; kk < FFN; kk += BK) {
#pragma unroll
        for (int i = 0; i < 2; i++) {
            int chunk = i * 256 + tid;
            int r = chunk >> 2, c = (chunk & 3) * 8;
            GLD16(act + (size_t)(row0 + r) * FFN + kk + c, As + chunk * 8);
        }
#pragma unroll
        for (int i = 0; i < 4; i++) {
            int idx = i * 256 + tid;
            int r = idx >> 3, c4 = idx & 7;
            float4 v = *(const float4*)(wb + (size_t)r * FFN + kk + c4 * 4);
            us4 o = { f2bf(v.x), f2bf(v.y), f2bf(v.z), f2bf(v.w) };
            *(us4*)&Bs[r * (BK + 8) + c4 * 4] = o;
        }
        __syncthreads();
        bf16x8 a[4], b[4];
#pragma unroll
        for (int mi = 0; mi < 4; mi++)
            a[mi] = *(const bf16x8*)&As[(wm * 64 + mi * 16 + m16) * BK + quad * 8];
#pragma unroll
        for (int ni = 0; ni < 4; ni++)
            b[ni] = *(const bf16x8*)&Bs[(wn * 64 + ni * 16 + m16) * (BK + 8) + quad * 8];
#pragma unroll
        for (int mi = 0; mi < 4; mi++)
#pragma unroll
            for (int ni = 0; ni < 4; ni++)
                acc[mi][ni] = __builtin_amdgcn_mfma_f32_16x16x32_bf16(a[mi], b[ni], acc[mi][ni], 0, 0, 0);
        __syncthreads();
    }
#pragma unroll
    for (int mi = 0; mi < 4; mi++)
#pragma unroll
        for (int ni = 0; ni < 4; ni++)
#pragma unroll
            for (int r = 0; r < 4; r++) {
                int grow = row0 + wm * 64 + mi * 16 + quad * 4 + r;
                int gcol = n0 + wn * 64 + ni * 16 + m16;
                yc[(size_t)grow * H + gcol] = acc[mi][ni][r];
            }
}

// ---------------- kernel 7: combine ----------------
__global__ void k_combine(const float4* __restrict__ yc4, const int* __restrict__ sel,
                          const int* __restrict__ posn, const int* __restrict__ base,
                          const float* __restrict__ wgt, float4* __restrict__ out4) {
    int t = blockIdx.x;
    int j = threadIdx.x;  // 256, H/4
    int r0 = base[sel[2 * t]] + posn[2 * t];
    int r1 = base[sel[2 * t + 1]] + posn[2 * t + 1];
    float w0 = wgt[2 * t], w1 = wgt[2 * t + 1];
    float4 a = yc4[(size_t)r0 * (H / 4) + j];
    float4 b = yc4[(size_t)r1 * (H / 4) + j];
    float4 o = { w0 * a.x + w1 * b.x, w0 * a.y + w1 * b.y,
                 w0 * a.z + w1 * b.z, w0 * a.w + w1 * b.w };
    out4[(size_t)t * (H / 4) + j] = o;
}

extern "C" void kernel_launch(void* const* d_in, const int* in_sizes, int n_in,
                              void* d_out, int out_size, void* d_ws, size_t ws_size,
                              hipStream_t stream) {
    const float* x   = (const float*)d_in[0];
    const float* gw  = (const float*)d_in[1];
    const float* w13 = (const float*)d_in[2];
    const float* w2  = (const float*)d_in[3];
    float* out    = (float*)d_out;
    float* logits = out + (size_t)TOK * H;

    char* ws = (char*)d_ws;
    int*   counts = (int*)ws;
    int*   base   = (int*)(ws + 256);
    int*   tile_e = (int*)(ws + 512);
    int*   sel    = (int*)(ws + 1024);
    int*   posn   = (int*)(ws + 1024 + 4 * PAIRS);
    float* wgt    = (float*)(ws + 1024 + 8 * PAIRS);
    u16*   xg     = (u16*)(ws + 65536);
    u16*   act    = xg + (size_t)ROWCAP * H;
    float* yc     = (float*)(act + (size_t)ROWCAP * FFN);

    k_zero<<<2560, 256, 0, stream>>>(counts, (uint4*)xg);
    k_router<<<TOK / 4, 256, 0, stream>>>(x, gw, logits, counts, sel, posn, wgt);
    k_prefix<<<1, 64, 0, stream>>>(counts, base, tile_e);
    k_gather<<<PAIRS, 64, 0, stream>>>((const float4*)x, sel, posn, base, xg);
    dim3 g1(MAXTILES, FFN / 64);
    k_gemm1<<<g1, 256, 0, stream>>>(xg, w13, act, tile_e);
    dim3 g2(MAXTILES, H / 128);
    k_gemm2<<<g2, 256, 0, stream>>>(act, w2, yc, tile_e);
    k_combine<<<TOK, 256, 0, stream>>>((const float4*)yc, sel, posn, base, wgt, (float4*)out);
}

// Round 3
// 720.006 us; speedup vs baseline: 1.0718x; 1.0718x over previous
//
#include <hip/hip_runtime.h>
#include <hip/hip_bf16.h>
#include <math.h>

#define H     1024
#define FFN   4096
#define NE    8
#define TOK   2048
#define PAIRS (TOK*2)
#define BM    128
#define BK    32
#define ROWCAP (PAIRS + NE*BM)   /* 5120 worst-case padded rows */
#define MAXTILES (ROWCAP/BM)     /* 40 */

typedef unsigned short u16;
typedef __attribute__((ext_vector_type(8))) __bf16 bf16x8;
typedef __attribute__((ext_vector_type(4))) float  f32x4;

// hardware v_cvt_pk_bf16_f32: 2 floats -> packed 2xbf16 in one inst
__device__ __forceinline__ unsigned cvt2(float a, float b) {
    __hip_bfloat162 h = __float22bfloat162_rn(float2{a, b});
    unsigned u;
    __builtin_memcpy(&u, &h, 4);
    return u;
}

#define GLD16(gp, lp) __builtin_amdgcn_global_load_lds( \
    (const __attribute__((address_space(1))) void*)(gp), \
    (__attribute__((address_space(3))) void*)(lp), 16, 0, 0)

// ---------------- kernel 1: init counts ----------------
__global__ void k_init(int* counts) {
    if (threadIdx.x < NE) counts[threadIdx.x] = 0;
}

// ---------------- kernel 2: router ----------------
__global__ void k_router(const float* __restrict__ x, const float* __restrict__ gw,
                         float* __restrict__ logits, int* counts,
                         int* __restrict__ sel, int* __restrict__ posn, float* __restrict__ wgt) {
    int lane = threadIdx.x & 63;
    int t = blockIdx.x * 4 + (threadIdx.x >> 6);
    float p[NE];
#pragma unroll
    for (int e = 0; e < NE; e++) p[e] = 0.f;
    for (int j = 0; j < H / 64; j++) {
        int h = lane + j * 64;
        float xv = x[(size_t)t * H + h];
#pragma unroll
        for (int e = 0; e < NE; e++) p[e] = fmaf(xv, gw[e * H + h], p[e]);
    }
#pragma unroll
    for (int off = 32; off; off >>= 1)
#pragma unroll
        for (int e = 0; e < NE; e++) p[e] += __shfl_xor(p[e], off, 64);
    if (lane == 0) {
        float mx = p[0];
#pragma unroll
        for (int e = 1; e < NE; e++) mx = fmaxf(mx, p[e]);
        float pe[NE];
#pragma unroll
        for (int e = 0; e < NE; e++) pe[e] = __expf(p[e] - mx);
        int i0 = 0;
#pragma unroll
        for (int e = 1; e < NE; e++) if (pe[e] > pe[i0]) i0 = e;
        int i1 = (i0 == 0) ? 1 : 0;
#pragma unroll
        for (int e = 0; e < NE; e++) if (e != i1 && e != i0 && pe[e] > pe[i1]) i1 = e;
        float w0 = pe[i0] / (pe[i0] + pe[i1]);
#pragma unroll
        for (int e = 0; e < NE; e++) logits[(size_t)t * NE + e] = p[e];
        int p0 = atomicAdd(&counts[i0], 1);
        int p1 = atomicAdd(&counts[i1], 1);
        sel[2 * t] = i0;  posn[2 * t] = p0;  wgt[2 * t] = w0;
        sel[2 * t + 1] = i1;  posn[2 * t + 1] = p1;  wgt[2 * t + 1] = 1.f - w0;
    }
}

// ---------------- kernel 3: prefix / tile map ----------------
__global__ void k_prefix(const int* __restrict__ counts, int* __restrict__ base,
                         int* __restrict__ tile_e) {
    if (threadIdx.x == 0) {
        int b = 0, tb = 0;
        for (int e = 0; e < NE; e++) {
            base[e] = b;
            int nt = (counts[e] + BM - 1) / BM;
            for (int i = 0; i < nt; i++) tile_e[tb++] = e;
            b += nt * BM;
        }
        base[NE] = b;
        while (tb < MAXTILES) tile_e[tb++] = -1;
    }
}

// ---------------- kernel 4: gather x -> bf16 compacted rows ----------------
// Pad rows of xg stay 0xAA-poisoned: bf16 0xAAAA = -1.2e-13 (finite, not NaN);
// pad-row outputs are never read by k_combine, so no zeroing needed.
__global__ void k_gather(const float4* __restrict__ x4, const int* __restrict__ sel,
                         const int* __restrict__ posn, const int* __restrict__ base,
                         u16* __restrict__ xg) {
    int p = blockIdx.x;
    int lane = threadIdx.x;       // 64 threads
    int t = p >> 1;
    int row = base[sel[p]] + posn[p];
#pragma unroll
    for (int i = 0; i < 4; i++) {
        int idx = i * 64 + lane;  // float4 index within row (256 per row)
        float4 v = x4[(size_t)t * (H / 4) + idx];
        uint2 o = { cvt2(v.x, v.y), cvt2(v.z, v.w) };
        *(uint2*)&xg[(size_t)row * H + idx * 4] = o;
    }
}

// ---------------- kernel 5: GEMM1  act = silu(x w1^T) * (x w3^T) ----------------
__global__ __launch_bounds__(256) void k_gemm1(const u16* __restrict__ xg,
                                               const float* __restrict__ w13,
                                               u16* __restrict__ act,
                                               const int* __restrict__ tile_e) {
    int e = tile_e[blockIdx.x];
    if (e < 0) return;
    __shared__ u16 As[BM * BK];          // 128x32 bf16, row-major K-contig
    __shared__ u16 Bs[2][64 * (BK + 8)]; // +8 pad breaks bank conflicts

    int tid = threadIdx.x;
    int lane = tid & 63, wave = tid >> 6;
    int quad = lane >> 4, m16 = lane & 15;
    int wm = wave >> 1, wn = wave & 1;
    int row0 = blockIdx.x * BM;
    int n0 = blockIdx.y * 64;
    const float* wb1 = w13 + ((size_t)e * 2 * FFN + n0) * H;
    const float* wb3 = w13 + ((size_t)e * 2 * FFN + FFN + n0) * H;

    f32x4 accg[4][2], accu[4][2];
#pragma unroll
    for (int mi = 0; mi < 4; mi++)
#pragma unroll
        for (int ni = 0; ni < 2; ni++) { accg[mi][ni] = {0.f,0.f,0.f,0.f}; accu[mi][ni] = {0.f,0.f,0.f,0.f}; }

    for (int kk = 0; kk < H; kk += BK) {
        // A tile: 128x32 bf16 = 512 x 16B chunks, 2 per thread, direct-to-LDS
#pragma unroll
        for (int i = 0; i < 2; i++) {
            int chunk = i * 256 + tid;
            int r = chunk >> 2, c = (chunk & 3) * 8;
            GLD16(xg + (size_t)(row0 + r) * H + kk + c, As + chunk * 8);
        }
        // B tiles (w1, w3): 64 rows x 8 float4 each; v_cvt_pk_bf16_f32 into padded LDS
#pragma unroll
        for (int i = 0; i < 2; i++) {
            int idx = i * 256 + tid;
            int r = idx >> 3, c4 = idx & 7;
            float4 v1 = *(const float4*)(wb1 + (size_t)r * H + kk + c4 * 4);
            float4 v3 = *(const float4*)(wb3 + (size_t)r * H + kk + c4 * 4);
            uint2 o1 = { cvt2(v1.x, v1.y), cvt2(v1.z, v1.w) };
            uint2 o3 = { cvt2(v3.x, v3.y), cvt2(v3.z, v3.w) };
            *(uint2*)&Bs[0][r * (BK + 8) + c4 * 4] = o1;
            *(uint2*)&Bs[1][r * (BK + 8) + c4 * 4] = o3;
        }
        __syncthreads();
        bf16x8 a[4], bg[2], bu[2];
#pragma unroll
        for (int mi = 0; mi < 4; mi++)
            a[mi] = *(const bf16x8*)&As[(wm * 64 + mi * 16 + m16) * BK + quad * 8];
#pragma unroll
        for (int ni = 0; ni < 2; ni++) {
            bg[ni] = *(const bf16x8*)&Bs[0][(wn * 32 + ni * 16 + m16) * (BK + 8) + quad * 8];
            bu[ni] = *(const bf16x8*)&Bs[1][(wn * 32 + ni * 16 + m16) * (BK + 8) + quad * 8];
        }
#pragma unroll
        for (int mi = 0; mi < 4; mi++)
#pragma unroll
            for (int ni = 0; ni < 2; ni++) {
                accg[mi][ni] = __builtin_amdgcn_mfma_f32_16x16x32_bf16(a[mi], bg[ni], accg[mi][ni], 0, 0, 0);
                accu[mi][ni] = __builtin_amdgcn_mfma_f32_16x16x32_bf16(a[mi], bu[ni], accu[mi][ni], 0, 0, 0);
            }
        __syncthreads();
    }
    // epilogue: silu(g)*u -> bf16 act (rows quad*4+r, r=0..3 are consecutive)
#pragma unroll
    for (int mi = 0; mi < 4; mi++)
#pragma unroll
        for (int ni = 0; ni < 2; ni++) {
            int gcol = n0 + wn * 32 + ni * 16 + m16;
            int grow = row0 + wm * 64 + mi * 16 + quad * 4;
#pragma unroll
            for (int r = 0; r < 4; r++) {
                float g = accg[mi][ni][r], u = accu[mi][ni][r];
                float hv = g * (1.f / (1.f + __expf(-g))) * u;
                unsigned pk = cvt2(hv, hv);
                act[(size_t)(grow + r) * FFN + gcol] = (u16)(pk & 0xffff);
            }
        }
}

// ---------------- kernel 6: GEMM2  yc = act w2^T  (split-K = 2) ----------------
__global__ __launch_bounds__(256) void k_gemm2(const u16* __restrict__ act,
                                               const float* __restrict__ w2,
                                               float* __restrict__ yc,
                                               const int* __restrict__ tile_e) {
    int e = tile_e[blockIdx.x];
    if (e < 0) return;
    __shared__ u16 As[BM * BK];
    __shared__ u16 Bs[BM * (BK + 8)];

    int tid = threadIdx.x;
    int lane = tid & 63, wave = tid >> 6;
    int quad = lane >> 4, m16 = lane & 15;
    int wm = wave >> 1, wn = wave & 1;
    int row0 = blockIdx.x * BM;
    int n0 = blockIdx.y * 128;
    int k0 = blockIdx.z * (FFN / 2);
    const float* wb = w2 + ((size_t)e * H + n0) * FFN;
    float* ycp = yc + (size_t)blockIdx.z * ROWCAP * H;

    f32x4 acc[4][4];
#pragma unroll
    for (int mi = 0; mi < 4; mi++)
#pragma unroll
        for (int ni = 0; ni < 4; ni++) acc[mi][ni] = {0.f,0.f,0.f,0.f};

    for (int kk = k0; kk < k0 + FFN / 2; kk += BK) {
#pragma unroll
        for (int i = 0; i < 2; i++) {
            int chunk = i * 256 + tid;
            int r = chunk >> 2, c = (chunk & 3) * 8;
            GLD16(act + (size_t)(row0 + r) * FFN + kk + c, As + chunk * 8);
        }
#pragma unroll
        for (int i = 0; i < 4; i++) {
            int idx = i * 256 + tid;
            int r = idx >> 3, c4 = idx & 7;
            float4 v = *(const float4*)(wb + (size_t)r * FFN + kk + c4 * 4);
            uint2 o = { cvt2(v.x, v.y), cvt2(v.z, v.w) };
            *(uint2*)&Bs[r * (BK + 8) + c4 * 4] = o;
        }
        __syncthreads();
        bf16x8 a[4], b[4];
#pragma unroll
        for (int mi = 0; mi < 4; mi++)
            a[mi] = *(const bf16x8*)&As[(wm * 64 + mi * 16 + m16) * BK + quad * 8];
#pragma unroll
        for (int ni = 0; ni < 4; ni++)
            b[ni] = *(const bf16x8*)&Bs[(wn * 64 + ni * 16 + m16) * (BK + 8) + quad * 8];
#pragma unroll
        for (int mi = 0; mi < 4; mi++)
#pragma unroll
            for (int ni = 0; ni < 4; ni++)
                acc[mi][ni] = __builtin_amdgcn_mfma_f32_16x16x32_bf16(a[mi], b[ni], acc[mi][ni], 0, 0, 0);
        __syncthreads();
    }
#pragma unroll
    for (int mi = 0; mi < 4; mi++)
#pragma unroll
        for (int ni = 0; ni < 4; ni++)
#pragma unroll
            for (int r = 0; r < 4; r++) {
                int grow = row0 + wm * 64 + mi * 16 + quad * 4 + r;
                int gcol = n0 + wn * 64 + ni * 16 + m16;
                ycp[(size_t)grow * H + gcol] = acc[mi][ni][r];
            }
}

// ---------------- kernel 7: combine (sums split-K partials) ----------------
__global__ void k_combine(const float4* __restrict__ yc4, const int* __restrict__ sel,
                          const int* __restrict__ posn, const int* __restrict__ base,
                          const float* __restrict__ wgt, float4* __restrict__ out4) {
    int t = blockIdx.x;
    int j = threadIdx.x;  // 256, H/4
    int r0 = base[sel[2 * t]] + posn[2 * t];
    int r1 = base[sel[2 * t + 1]] + posn[2 * t + 1];
    float w0 = wgt[2 * t], w1 = wgt[2 * t + 1];
    const size_t P = (size_t)ROWCAP * (H / 4);
    float4 a0 = yc4[(size_t)r0 * (H / 4) + j];
    float4 a1 = yc4[(size_t)r0 * (H / 4) + j + P];
    float4 b0 = yc4[(size_t)r1 * (H / 4) + j];
    float4 b1 = yc4[(size_t)r1 * (H / 4) + j + P];
    float4 o = { w0 * (a0.x + a1.x) + w1 * (b0.x + b1.x),
                 w0 * (a0.y + a1.y) + w1 * (b0.y + b1.y),
                 w0 * (a0.z + a1.z) + w1 * (b0.z + b1.z),
                 w0 * (a0.w + a1.w) + w1 * (b0.w + b1.w) };
    out4[(size_t)t * (H / 4) + j] = o;
}

extern "C" void kernel_launch(void* const* d_in, const int* in_sizes, int n_in,
                              void* d_out, int out_size, void* d_ws, size_t ws_size,
                              hipStream_t stream) {
    const float* x   = (const float*)d_in[0];
    const float* gw  = (const float*)d_in[1];
    const float* w13 = (const float*)d_in[2];
    const float* w2  = (const float*)d_in[3];
    float* out    = (float*)d_out;
    float* logits = out + (size_t)TOK * H;

    char* ws = (char*)d_ws;
    int*   counts = (int*)ws;
    int*   base   = (int*)(ws + 256);
    int*   tile_e = (int*)(ws + 512);
    int*   sel    = (int*)(ws + 1024);
    int*   posn   = (int*)(ws + 1024 + 4 * PAIRS);
    float* wgt    = (float*)(ws + 1024 + 8 * PAIRS);
    u16*   xg     = (u16*)(ws + 65536);
    u16*   act    = xg + (size_t)ROWCAP * H;
    float* yc     = (float*)(act + (size_t)ROWCAP * FFN);  // 2 split-K partials

    k_init<<<1, 64, 0, stream>>>(counts);
    k_router<<<TOK / 4, 256, 0, stream>>>(x, gw, logits, counts, sel, posn, wgt);
    k_prefix<<<1, 64, 0, stream>>>(counts, base, tile_e);
    k_gather<<<PAIRS, 64, 0, stream>>>((const float4*)x, sel, posn, base, xg);
    dim3 g1(MAXTILES, FFN / 64);
    k_gemm1<<<g1, 256, 0, stream>>>(xg, w13, act, tile_e);
    dim3 g2(MAXTILES, H / 128, 2);
    k_gemm2<<<g2, 256, 0, stream>>>(act, w2, yc, tile_e);
    k_combine<<<TOK, 256, 0, stream>>>((const float4*)yc, sel, posn, base, wgt, (float4*)out);
}